// Round 17
// baseline (477.688 us; speedup 1.0000x reference)
//
#include <hip/hip_runtime.h>

#define N_NODES 50000
#define N_EDGES_C 25000
#define NNZ_C 400000
#define SCHUNK 2048

typedef __bf16 bf16;
typedef __bf16 bf16x8 __attribute__((ext_vector_type(8)));
typedef __bf16 bf16x4 __attribute__((ext_vector_type(4)));
typedef float f32x4 __attribute__((ext_vector_type(4)));
typedef float f32x8 __attribute__((ext_vector_type(8)));
typedef unsigned int u32x4 __attribute__((ext_vector_type(4)));

typedef __attribute__((address_space(1))) const void as1_cvoid;
typedef __attribute__((address_space(3))) void as3_void;

__device__ __forceinline__ void gload_lds16(const bf16* g, bf16* l) {
  __builtin_amdgcn_global_load_lds((as1_cvoid*)g, (as3_void*)l, 16, 0, 0);
}

// nontemporal 16B store of 8 bf16 (streaming output, no reuse in-kernel)
__device__ __forceinline__ void nt_store8(bf16* p, bf16x8 v) {
  u32x4 r;
  __builtin_memcpy(&r, &v, 16);
  __builtin_nontemporal_store(r, (u32x4*)p);
}
__device__ __forceinline__ void nt_store_bf16(bf16* p, bf16 v) {
  unsigned short r;
  __builtin_memcpy(&r, &v, 2);
  __builtin_nontemporal_store(r, (unsigned short*)p);
}

// ---------------- X convert: f32 -> bf16, coalesced, NT output ----------------
__global__ __launch_bounds__(256) void convert_x(const float* __restrict__ X,
                                                 bf16* __restrict__ Xb) {
  const size_t i = ((size_t)blockIdx.x * 256 + threadIdx.x) * 8;
  float4 v0 = *(const float4*)(X + i);
  float4 v1 = *(const float4*)(X + i + 4);
  bf16x8 o;
  o[0] = (bf16)v0.x; o[1] = (bf16)v0.y; o[2] = (bf16)v0.z; o[3] = (bf16)v0.w;
  o[4] = (bf16)v1.x; o[5] = (bf16)v1.y; o[6] = (bf16)v1.z; o[7] = (bf16)v1.w;
  nt_store8(Xb + i, o);
}

// ---------------- weights: tiled W1/W2 transpose + Wout ----------------
__global__ void weights_kernel(const float* __restrict__ W1, const float* __restrict__ W2,
                               const float* __restrict__ Wout,
                               bf16* __restrict__ Wt1, bf16* __restrict__ Wt2,
                               bf16* __restrict__ Wt3) {
  const int b = blockIdx.x;
  const int t = threadIdx.x;
  if (b < 128) {
    const int isW1 = (b < 64);
    const float* W = isW1 ? W1 : W2;
    bf16* Wt = isW1 ? Wt1 : Wt2;
    const int tb = isW1 ? b : (b - 64);
    const int k0 = (tb & 7) * 64, n0 = (tb >> 3) * 64;
    __shared__ float tile[64][65];
#pragma unroll
    for (int i = 0; i < 16; ++i) {
      int li = i * 256 + t;
      int kr = li >> 6, nc = li & 63;
      tile[kr][nc] = W[(size_t)(k0 + kr) * 512 + n0 + nc];
    }
    __syncthreads();
#pragma unroll
    for (int i = 0; i < 16; ++i) {
      int lo = i * 256 + t;
      int nr = lo >> 6, kc = lo & 63;
      Wt[(size_t)(n0 + nr) * 512 + k0 + kc] = (bf16)tile[kc][nr];
    }
  } else {
    int idx = (b - 128) * 256 + t;
    int n = idx >> 9, k = idx & 511;
    Wt3[idx] = (n < 40) ? (bf16)Wout[(size_t)k * 40 + n] : (bf16)0.0f;
  }
}

// ---------------- histogram ----------------
__global__ void hist_kernel(const int* __restrict__ vtx, const int* __restrict__ edg,
                            int* __restrict__ cntV, int* __restrict__ cntE, int nnz) {
  int i = blockIdx.x * blockDim.x + threadIdx.x;
  if (i < nnz) {
    atomicAdd(&cntV[vtx[i]], 1);
    atomicAdd(&cntE[edg[i]], 1);
  }
}

__global__ void scan_part2(const int* __restrict__ cntE, const int* __restrict__ cntV,
                           int* __restrict__ partE, int* __restrict__ partV,
                           int nbE) {
  __shared__ int red[256];
  const int t = threadIdx.x;
  const int isV = (blockIdx.x >= nbE);
  const int b = isV ? (blockIdx.x - nbE) : blockIdx.x;
  const int* cnt = isV ? cntV : cntE;
  const int n = isV ? N_NODES : N_EDGES_C;
  const int base = b * SCHUNK + t * 8;
  int s = 0;
#pragma unroll
  for (int q = 0; q < 8; ++q) {
    int i = base + q;
    if (i < n) s += cnt[i];
  }
  red[t] = s;
  __syncthreads();
  for (int d = 128; d > 0; d >>= 1) {
    if (t < d) red[t] += red[t + d];
    __syncthreads();
  }
  if (t == 0) (isV ? partV : partE)[b] = red[0];
}

__global__ void scan_mid2(int* __restrict__ partE, int* __restrict__ partV,
                          int* __restrict__ eoff, int* __restrict__ voff,
                          int nbE, int nbV) {
  const int wv = threadIdx.x >> 6;
  const int lane = threadIdx.x & 63;
  int* part = wv ? partV : partE;
  int* off = wv ? voff : eoff;
  const int np = wv ? nbV : nbE;
  const int n = wv ? N_NODES : N_EDGES_C;
  int orig = (lane < np) ? part[lane] : 0;
  int v = orig;
  for (int o = 1; o < 64; o <<= 1) {
    int x = __shfl_up(v, o);
    if (lane >= o) v += x;
  }
  if (lane < np) part[lane] = v - orig;
  if (lane == 63) off[n] = v;
}

__global__ void scan_final2(const int* __restrict__ cntE, const int* __restrict__ cntV,
                            const int* __restrict__ partE, const int* __restrict__ partV,
                            int* __restrict__ eoff, int* __restrict__ voff, int nbE) {
  __shared__ int tsum[256];
  const int t = threadIdx.x;
  const int isV = (blockIdx.x >= nbE);
  const int b = isV ? (blockIdx.x - nbE) : blockIdx.x;
  const int* cnt = isV ? cntV : cntE;
  const int* part = isV ? partV : partE;
  int* off = isV ? voff : eoff;
  const int n = isV ? N_NODES : N_EDGES_C;
  const int base = b * SCHUNK + t * 8;
  int loc[8];
  int s = 0;
#pragma unroll
  for (int q = 0; q < 8; ++q) {
    int i = base + q;
    loc[q] = (i < n) ? cnt[i] : 0;
    s += loc[q];
  }
  tsum[t] = s;
  __syncthreads();
  for (int d = 1; d < 256; d <<= 1) {
    int x = (t >= d) ? tsum[t - d] : 0;
    __syncthreads();
    tsum[t] += x;
    __syncthreads();
  }
  int run = part[b] + ((t > 0) ? tsum[t - 1] : 0);
#pragma unroll
  for (int q = 0; q < 8; ++q) {
    int i = base + q;
    if (i < n) off[i] = run;
    run += loc[q];
  }
}

__global__ void scatter_kernel(const int* __restrict__ vtx, const int* __restrict__ edg,
                               const int* __restrict__ eoff, const int* __restrict__ voff,
                               int* __restrict__ curE, int* __restrict__ curV,
                               int* __restrict__ evtx, int* __restrict__ vedg, int nnz) {
  int i = blockIdx.x * blockDim.x + threadIdx.x;
  if (i < nnz) {
    int e = edg[i], v = vtx[i];
    int p = atomicAdd(&curE[e], 1);
    evtx[eoff[e] + p] = v;
    int q = atomicAdd(&curV[v], 1);
    vedg[voff[v] + q] = e;
  }
}

// ---------------- GEMM: BK=64, swizzled LDS, dbuf counted-vmcnt, XCD-chunked, NT C-writes ----------------
template <int TN>
__global__ __launch_bounds__(256) void gemm_bf16_kernel(
    const bf16* __restrict__ A, const bf16* __restrict__ B,
    bf16* __restrict__ Cb, int M, int K, int ldC, int Nstore) {
  __shared__ bf16 Al[2][128][64];
  __shared__ bf16 Bl[2][TN][64];
  const int bid = blockIdx.x;
  const int cpx = gridDim.x >> 3;
  const int wid = (bid & 7) * cpx + (bid >> 3);
  const int MBLK = (M + 127) >> 7;
  int mIdx, nIdx;
  if (TN == 128) { mIdx = wid >> 2; nIdx = wid & 3; }
  else           { mIdx = wid;      nIdx = 0; }
  if (mIdx >= MBLK) return;
  const int m0 = mIdx * 128;
  const int n0 = nIdx * TN;

  const int t = threadIdx.x;
  const int w = t >> 6, lane = t & 63;
  const int rb = (TN == 128) ? ((w >> 1) * 64) : (w * 32);
  const int cb = (TN == 128) ? ((w & 1) * 64) : 0;
  const int MF = (TN == 128) ? 4 : 2;
  const int lr = lane & 15;
  const int ls = lane >> 4;

  f32x4 acc[(TN == 128) ? 4 : 2][4];
#pragma unroll
  for (int m = 0; m < MF; ++m)
#pragma unroll
    for (int n = 0; n < 4; ++n) acc[m][n] = (f32x4){0.f, 0.f, 0.f, 0.f};

  const int srow8 = lane >> 3;
  const int scol = ((lane & 7) ^ srow8) << 3;

  const bf16* Abase = A + (size_t)m0 * K;
  const bf16* Bbase = B + (size_t)n0 * K;

#define STAGE(tile, bsel)                                                          \
  {                                                                                \
    const int kk_ = (tile) * 64;                                                   \
    _Pragma("unroll")                                                              \
    for (int q = 0; q < 4; ++q) {                                                  \
      const int row = w * 32 + q * 8 + srow8;                                      \
      gload_lds16(Abase + (size_t)row * K + kk_ + scol, &Al[bsel][w*32+q*8][0]);   \
    }                                                                              \
    _Pragma("unroll")                                                              \
    for (int q = 0; q < TN / 32; ++q) {                                            \
      const int row = w * (TN / 4) + q * 8 + srow8;                                \
      gload_lds16(Bbase + (size_t)row * K + kk_ + scol,                            \
                  &Bl[bsel][w * (TN / 4) + q * 8][0]);                             \
    }                                                                              \
  }

  const int NT = K >> 6;
  STAGE(0, 0);
  for (int tt = 0; tt < NT; ++tt) {
    const int cur = tt & 1;
    if (tt + 1 < NT) {
      STAGE(tt + 1, cur ^ 1);
      if (TN == 128) asm volatile("s_waitcnt vmcnt(8)" ::: "memory");
      else           asm volatile("s_waitcnt vmcnt(6)" ::: "memory");
    } else {
      asm volatile("s_waitcnt vmcnt(0)" ::: "memory");
    }
    __builtin_amdgcn_s_barrier();
    __builtin_amdgcn_s_setprio(1);
#pragma unroll
    for (int ks = 0; ks < 2; ++ks) {
      bf16x8 af[(TN == 128) ? 4 : 2], bfr[4];
#pragma unroll
      for (int m = 0; m < MF; ++m) {
        const int R = rb + m * 16 + lr;
        af[m] = *(const bf16x8*)(&Al[cur][R][((ks * 4 + ls) ^ (lr & 7)) << 3]);
      }
#pragma unroll
      for (int n = 0; n < 4; ++n) {
        const int R = cb + n * 16 + lr;
        bfr[n] = *(const bf16x8*)(&Bl[cur][R][((ks * 4 + ls) ^ (lr & 7)) << 3]);
      }
#pragma unroll
      for (int m = 0; m < MF; ++m)
#pragma unroll
        for (int n = 0; n < 4; ++n)
          acc[m][n] = __builtin_amdgcn_mfma_f32_16x16x32_bf16(af[m], bfr[n], acc[m][n], 0, 0, 0);
    }
    __builtin_amdgcn_s_setprio(0);
    __builtin_amdgcn_s_barrier();
  }
#undef STAGE

  const int cr = (lane >> 4) << 2;  // C/D: col = lane&15, row = (lane>>4)*4 + i
  const int cc = lane & 15;
#pragma unroll
  for (int m = 0; m < MF; ++m) {
#pragma unroll
    for (int n = 0; n < 4; ++n) {
      int gc = n0 + cb + n * 16 + cc;
      if (gc >= Nstore) continue;
#pragma unroll
      for (int i = 0; i < 4; ++i) {
        int gr = m0 + rb + m * 16 + cr + i;
        if (gr < M) nt_store_bf16(&Cb[(size_t)gr * ldC + gc], (bf16)acc[m][n][i]);
      }
    }
  }
}

// ---------------- wave-per-edge aggregation (bf16, C=512), NT output ----------------
__global__ __launch_bounds__(256) void edge_agg_w(
    const bf16* __restrict__ Y, const int* __restrict__ eoff, const int* __restrict__ evtx,
    const float* __restrict__ degE, bf16* __restrict__ Xe, int nE) {
  const int wv = (blockIdx.x * 256 + threadIdx.x) >> 6;
  if (wv >= nE) return;
  const int lane = threadIdx.x & 63;
  const int beg = eoff[wv], end = eoff[wv + 1];
  const int cnt = end - beg;
  const float scale = (cnt > 0) ? degE[wv] / (float)cnt : 0.f;
  float acc[8] = {0.f, 0.f, 0.f, 0.f, 0.f, 0.f, 0.f, 0.f};
  for (int base = beg; base < end; base += 64) {
    const int nb = min(64, end - base);
    int myidx = (lane < nb) ? evtx[base + lane] : 0;
    int j = 0;
    for (; j + 1 < nb; j += 2) {
      const int i0 = __shfl(myidx, j);
      const int i1 = __shfl(myidx, j + 1);
      bf16x8 v0 = *(const bf16x8*)(Y + (size_t)i0 * 512 + lane * 8);
      bf16x8 v1 = *(const bf16x8*)(Y + (size_t)i1 * 512 + lane * 8);
#pragma unroll
      for (int q = 0; q < 8; ++q) acc[q] += (float)v0[q] + (float)v1[q];
    }
    if (j < nb) {
      const int i0 = __shfl(myidx, j);
      bf16x8 v0 = *(const bf16x8*)(Y + (size_t)i0 * 512 + lane * 8);
#pragma unroll
      for (int q = 0; q < 8; ++q) acc[q] += (float)v0[q];
    }
  }
  bf16x8 o;
#pragma unroll
  for (int q = 0; q < 8; ++q) o[q] = (bf16)(acc[q] * scale);
  nt_store8(Xe + (size_t)wv * 512 + lane * 8, o);
}

// ---------------- wave-per-vertex aggregation (bf16, relu, C=512), NT output ----------------
__global__ __launch_bounds__(256) void vtx_agg_w(
    const bf16* __restrict__ Xe, const int* __restrict__ voff, const int* __restrict__ vedg,
    const float* __restrict__ degV, bf16* __restrict__ outB, int nV) {
  const int wv = (blockIdx.x * 256 + threadIdx.x) >> 6;
  if (wv >= nV) return;
  const int lane = threadIdx.x & 63;
  const int beg = voff[wv], end = voff[wv + 1];
  const float dv = degV[wv];
  float acc[8] = {0.f, 0.f, 0.f, 0.f, 0.f, 0.f, 0.f, 0.f};
  for (int base = beg; base < end; base += 64) {
    const int nb = min(64, end - base);
    int myidx = (lane < nb) ? vedg[base + lane] : 0;
    int j = 0;
    for (; j + 1 < nb; j += 2) {
      const int i0 = __shfl(myidx, j);
      const int i1 = __shfl(myidx, j + 1);
      bf16x8 v0 = *(const bf16x8*)(Xe + (size_t)i0 * 512 + lane * 8);
      bf16x8 v1 = *(const bf16x8*)(Xe + (size_t)i1 * 512 + lane * 8);
#pragma unroll
      for (int q = 0; q < 8; ++q) acc[q] += (float)v0[q] + (float)v1[q];
    }
    if (j < nb) {
      const int i0 = __shfl(myidx, j);
      bf16x8 v0 = *(const bf16x8*)(Xe + (size_t)i0 * 512 + lane * 8);
#pragma unroll
      for (int q = 0; q < 8; ++q) acc[q] += (float)v0[q];
    }
  }
  bf16x8 o;
#pragma unroll
  for (int q = 0; q < 8; ++q) o[q] = (bf16)fmaxf(acc[q] * dv, 0.f);
  nt_store8(outB + (size_t)wv * 512 + lane * 8, o);
}

// ---------------- layer-3 edge aggregation, octet layout (C=64 padded), NT output ----------------
__global__ __launch_bounds__(256) void edge_agg40_w8(
    const bf16* __restrict__ Y, const int* __restrict__ eoff, const int* __restrict__ evtx,
    const float* __restrict__ degE, bf16* __restrict__ Xe, int nE) {
  const int wv = (blockIdx.x * 256 + threadIdx.x) >> 6;
  if (wv >= nE) return;
  const int lane = threadIdx.x & 63;
  const int g = lane >> 3, c = lane & 7;
  const int beg = eoff[wv], end = eoff[wv + 1];
  const int cnt = end - beg;
  const float scale = (cnt > 0) ? degE[wv] / (float)cnt : 0.f;
  float acc[8] = {0.f, 0.f, 0.f, 0.f, 0.f, 0.f, 0.f, 0.f};
  for (int base = beg; base < end; base += 64) {
    const int nb = min(64, end - base);
    int myidx = (lane < nb) ? evtx[base + lane] : 0;
    for (int inner = 0; inner < 8; ++inner) {
      const int r = inner * 8 + g;
      if (inner * 8 >= nb) break;
      const int ridx = __shfl(myidx, r);
      if (r < nb) {
        bf16x8 v = *(const bf16x8*)(Y + (size_t)ridx * 64 + c * 8);
#pragma unroll
        for (int q = 0; q < 8; ++q) acc[q] += (float)v[q];
      }
    }
  }
#pragma unroll
  for (int o = 8; o < 64; o <<= 1)
#pragma unroll
    for (int q = 0; q < 8; ++q) acc[q] += __shfl_xor(acc[q], o);
  if (lane < 8) {
    bf16x8 o;
#pragma unroll
    for (int q = 0; q < 8; ++q) o[q] = (bf16)(acc[q] * scale);
    nt_store8(Xe + (size_t)wv * 64 + lane * 8, o);
  }
}

// ---------------- final vertex aggregation + log_softmax, octet layout ----------------
__global__ __launch_bounds__(256) void vtx_agg_lsm8(
    const bf16* __restrict__ Xe, const int* __restrict__ voff, const int* __restrict__ vedg,
    const float* __restrict__ degV, float* __restrict__ out, int nV) {
  const int wv = (blockIdx.x * 256 + threadIdx.x) >> 6;
  if (wv >= nV) return;
  const int lane = threadIdx.x & 63;
  const int g = lane >> 3, c = lane & 7;
  const int beg = voff[wv], end = voff[wv + 1];
  const float dv = degV[wv];
  float acc[8] = {0.f, 0.f, 0.f, 0.f, 0.f, 0.f, 0.f, 0.f};
  for (int base = beg; base < end; base += 64) {
    const int nb = min(64, end - base);
    int myidx = (lane < nb) ? vedg[base + lane] : 0;
    for (int inner = 0; inner < 8; ++inner) {
      const int r = inner * 8 + g;
      if (inner * 8 >= nb) break;
      const int ridx = __shfl(myidx, r);
      if (r < nb) {
        bf16x8 v = *(const bf16x8*)(Xe + (size_t)ridx * 64 + c * 8);
#pragma unroll
        for (int q = 0; q < 8; ++q) acc[q] += (float)v[q];
      }
    }
  }
#pragma unroll
  for (int o = 8; o < 64; o <<= 1)
#pragma unroll
    for (int q = 0; q < 8; ++q) acc[q] += __shfl_xor(acc[q], o);
  float l[8];
#pragma unroll
  for (int q = 0; q < 8; ++q) l[q] = acc[q] * dv;
  float lm = -3.4e38f;
  if (c < 5) {
#pragma unroll
    for (int q = 0; q < 8; ++q) lm = fmaxf(lm, l[q]);
  }
#pragma unroll
  for (int o = 1; o < 8; o <<= 1) lm = fmaxf(lm, __shfl_xor(lm, o));
  float ls = 0.f;
  if (c < 5) {
#pragma unroll
    for (int q = 0; q < 8; ++q) ls += expf(l[q] - lm);
  }
#pragma unroll
  for (int o = 1; o < 8; o <<= 1) ls += __shfl_xor(ls, o);
  const float lg = logf(ls);
  if (lane < 5) {
    f32x8 w;
#pragma unroll
    for (int q = 0; q < 8; ++q) w[q] = l[q] - lm - lg;
    *(f32x8*)(out + (size_t)wv * 40 + lane * 8) = w;
  }
}

extern "C" void kernel_launch(void* const* d_in, const int* in_sizes, int n_in,
                              void* d_out, int out_size, void* d_ws, size_t ws_size,
                              hipStream_t stream) {
  (void)in_sizes; (void)n_in; (void)out_size; (void)ws_size;
  const float* X = (const float*)d_in[0];
  const int* vertex = (const int*)d_in[1];
  const int* edges = (const int*)d_in[2];
  const float* W1 = (const float*)d_in[3];
  const float* W2 = (const float*)d_in[4];
  const float* Wout = (const float*)d_in[5];
  const float* degE = (const float*)d_in[6];
  const float* degV = (const float*)d_in[7];
  float* out = (float*)d_out;

  char* ws = (char*)d_ws;
  size_t off = 0;
  auto alloc = [&](size_t bytes) -> void* {
    void* p = ws + off;
    off += (bytes + 255) & ~(size_t)255;
    return p;
  };
  bf16* Xb  = (bf16*)alloc((size_t)N_NODES * 512 * sizeof(bf16));
  bf16* XeB = (bf16*)alloc((size_t)N_EDGES_C * 512 * sizeof(bf16));
  bf16* YeB = (bf16*)alloc((size_t)N_EDGES_C * 512 * sizeof(bf16));
  bf16* Y40b  = (bf16*)alloc((size_t)N_NODES * 64 * sizeof(bf16));
  bf16* Xe40b = (bf16*)alloc((size_t)N_EDGES_C * 64 * sizeof(bf16));
  bf16* Wt1 = (bf16*)alloc((size_t)512 * 512 * sizeof(bf16));
  bf16* Wt2 = (bf16*)alloc((size_t)512 * 512 * sizeof(bf16));
  bf16* Wt3 = (bf16*)alloc((size_t)64 * 512 * sizeof(bf16));
  int* eoff = (int*)alloc((N_EDGES_C + 1) * sizeof(int));
  int* voff = (int*)alloc((N_NODES + 1) * sizeof(int));
  int* evtx = (int*)alloc((size_t)NNZ_C * sizeof(int));
  int* vedg = (int*)alloc((size_t)NNZ_C * sizeof(int));
  int* cnts = (int*)alloc((size_t)(2 * (N_EDGES_C + N_NODES)) * sizeof(int));
  int* cntE = cnts;
  int* cntV = cnts + N_EDGES_C;
  int* curE = cnts + N_EDGES_C + N_NODES;
  int* curV = cnts + 2 * N_EDGES_C + N_NODES;
  int* partE = (int*)alloc(64 * sizeof(int));
  int* partV = (int*)alloc(64 * sizeof(int));

  hipMemsetAsync(cnts, 0, (size_t)(2 * (N_EDGES_C + N_NODES)) * sizeof(int), stream);

  convert_x<<<(N_NODES * 512) / 2048, 256, 0, stream>>>(X, Xb);
  hist_kernel<<<(NNZ_C + 255) / 256, 256, 0, stream>>>(vertex, edges, cntV, cntE, NNZ_C);
  weights_kernel<<<256, 256, 0, stream>>>(W1, W2, Wout, Wt1, Wt2, Wt3);

  const int nbE = (N_EDGES_C + SCHUNK - 1) / SCHUNK;  // 13
  const int nbV = (N_NODES + SCHUNK - 1) / SCHUNK;    // 25
  scan_part2<<<nbE + nbV, 256, 0, stream>>>(cntE, cntV, partE, partV, nbE);
  scan_mid2<<<1, 128, 0, stream>>>(partE, partV, eoff, voff, nbE, nbV);
  scan_final2<<<nbE + nbV, 256, 0, stream>>>(cntE, cntV, partE, partV, eoff, voff, nbE);

  scatter_kernel<<<(NNZ_C + 255) / 256, 256, 0, stream>>>(vertex, edges, eoff, voff,
                                                          curE, curV, evtx, vedg, NNZ_C);

  const int MBV = (N_NODES + 127) / 128;          // 391
  const int MBE = (N_EDGES_C + 127) / 128;        // 196
  const int GE512 = ((MBE * 4 + 7) / 8) * 8;      // 784
  const int GV64  = ((MBV + 7) / 8) * 8;          // 392

  // ---- layer 1: edge_agg(X) -> GEMM (25K rows) -> vtx_agg ----
  edge_agg_w<<<(N_EDGES_C + 3) / 4, 256, 0, stream>>>(Xb, eoff, evtx, degE, XeB, N_EDGES_C);
  gemm_bf16_kernel<128><<<GE512, 256, 0, stream>>>(XeB, Wt1, YeB, N_EDGES_C, 512, 512, 512);
  vtx_agg_w<<<(N_NODES + 3) / 4, 256, 0, stream>>>(YeB, voff, vedg, degV, Xb, N_NODES);

  // ---- layer 2 ----
  edge_agg_w<<<(N_EDGES_C + 3) / 4, 256, 0, stream>>>(Xb, eoff, evtx, degE, XeB, N_EDGES_C);
  gemm_bf16_kernel<128><<<GE512, 256, 0, stream>>>(XeB, Wt2, YeB, N_EDGES_C, 512, 512, 512);
  vtx_agg_w<<<(N_NODES + 3) / 4, 256, 0, stream>>>(YeB, voff, vedg, degV, Xb, N_NODES);

  // ---- layer 3 ----
  gemm_bf16_kernel<64><<<GV64, 256, 0, stream>>>(Xb, Wt3, Y40b, N_NODES, 512, 64, 64);
  edge_agg40_w8<<<(N_EDGES_C + 3) / 4, 256, 0, stream>>>(Y40b, eoff, evtx, degE, Xe40b, N_EDGES_C);
  vtx_agg_lsm8<<<(N_NODES + 3) / 4, 256, 0, stream>>>(Xe40b, voff, vedg, degV, out, N_NODES);
}

// Round 18
// 454.123 us; speedup vs baseline: 1.0519x; 1.0519x over previous
//
#include <hip/hip_runtime.h>

#define N_NODES 50000
#define N_EDGES_C 25000
#define NNZ_C 400000
#define SCHUNK 2048

typedef __bf16 bf16;
typedef __bf16 bf16x8 __attribute__((ext_vector_type(8)));
typedef __bf16 bf16x4 __attribute__((ext_vector_type(4)));
typedef float f32x4 __attribute__((ext_vector_type(4)));
typedef float f32x8 __attribute__((ext_vector_type(8)));

typedef __attribute__((address_space(1))) const void as1_cvoid;
typedef __attribute__((address_space(3))) void as3_void;

__device__ __forceinline__ void gload_lds16(const bf16* g, bf16* l) {
  __builtin_amdgcn_global_load_lds((as1_cvoid*)g, (as3_void*)l, 16, 0, 0);
}

// ---------------- prep: histogram + tiled W transposes + X convert ----------------
#define PREP_H ((NNZ_C + 255) / 256)           // 1563 histogram blocks
#define PREP_T1 (PREP_H)
#define PREP_T2 (PREP_T1 + 64)
#define PREP_WO (PREP_T2 + 64)
#define PREP_X  (PREP_WO + 128)
#define PREP_TOTAL (PREP_X + 12500)
__global__ void prep_conv(const float* __restrict__ W1, const float* __restrict__ W2,
                          const float* __restrict__ Wout, const float* __restrict__ X,
                          bf16* __restrict__ Wt1, bf16* __restrict__ Wt2,
                          bf16* __restrict__ Wt3,  bf16* __restrict__ Xb,
                          const int* __restrict__ vtx, const int* __restrict__ edg,
                          int* __restrict__ cntV, int* __restrict__ cntE) {
  const int b = blockIdx.x;
  const int t = threadIdx.x;
  if (b < PREP_H) {                       // histogram
    int i = b * 256 + t;
    if (i < NNZ_C) {
      atomicAdd(&cntV[vtx[i]], 1);
      atomicAdd(&cntE[edg[i]], 1);
    }
  } else if (b < PREP_WO) {               // W1/W2: 64x64 LDS-tiled transpose
    const int isW1 = (b < PREP_T2);
    const float* W = isW1 ? W1 : W2;
    bf16* Wt = isW1 ? Wt1 : Wt2;
    const int tb = isW1 ? (b - PREP_T1) : (b - PREP_T2);
    const int k0 = (tb & 7) * 64, n0 = (tb >> 3) * 64;
    __shared__ float tile[64][65];
#pragma unroll
    for (int i = 0; i < 16; ++i) {
      int li = i * 256 + t;
      int kr = li >> 6, nc = li & 63;
      tile[kr][nc] = W[(size_t)(k0 + kr) * 512 + n0 + nc];
    }
    __syncthreads();
#pragma unroll
    for (int i = 0; i < 16; ++i) {
      int lo = i * 256 + t;
      int nr = lo >> 6, kc = lo & 63;
      Wt[(size_t)(n0 + nr) * 512 + k0 + kc] = (bf16)tile[kc][nr];
    }
  } else if (b < PREP_X) {                // Wout: 64 rows x 512, cols >=40 zero
    int idx = (b - PREP_WO) * 256 + t;
    int n = idx >> 9, k = idx & 511;
    Wt3[idx] = (n < 40) ? (bf16)Wout[(size_t)k * 40 + n] : (bf16)0.0f;
  } else {                                // X convert f32 -> bf16
    size_t i = ((size_t)(b - PREP_X) * 256 + t) * 8;
    float4 v0 = *(const float4*)(X + i);
    float4 v1 = *(const float4*)(X + i + 4);
    bf16x8 o;
    o[0] = (bf16)v0.x; o[1] = (bf16)v0.y; o[2] = (bf16)v0.z; o[3] = (bf16)v0.w;
    o[4] = (bf16)v1.x; o[5] = (bf16)v1.y; o[6] = (bf16)v1.z; o[7] = (bf16)v1.w;
    *(bf16x8*)(Xb + i) = o;
  }
}

__global__ void scan_part2(const int* __restrict__ cntE, const int* __restrict__ cntV,
                           int* __restrict__ partE, int* __restrict__ partV,
                           int nbE) {
  __shared__ int red[256];
  const int t = threadIdx.x;
  const int isV = (blockIdx.x >= nbE);
  const int b = isV ? (blockIdx.x - nbE) : blockIdx.x;
  const int* cnt = isV ? cntV : cntE;
  const int n = isV ? N_NODES : N_EDGES_C;
  const int base = b * SCHUNK + t * 8;
  int s = 0;
#pragma unroll
  for (int q = 0; q < 8; ++q) {
    int i = base + q;
    if (i < n) s += cnt[i];
  }
  red[t] = s;
  __syncthreads();
  for (int d = 128; d > 0; d >>= 1) {
    if (t < d) red[t] += red[t + d];
    __syncthreads();
  }
  if (t == 0) (isV ? partV : partE)[b] = red[0];
}

__global__ void scan_mid2(int* __restrict__ partE, int* __restrict__ partV,
                          int* __restrict__ eoff, int* __restrict__ voff,
                          int nbE, int nbV) {
  const int wv = threadIdx.x >> 6;
  const int lane = threadIdx.x & 63;
  int* part = wv ? partV : partE;
  int* off = wv ? voff : eoff;
  const int np = wv ? nbV : nbE;
  const int n = wv ? N_NODES : N_EDGES_C;
  int orig = (lane < np) ? part[lane] : 0;
  int v = orig;
  for (int o = 1; o < 64; o <<= 1) {
    int x = __shfl_up(v, o);
    if (lane >= o) v += x;
  }
  if (lane < np) part[lane] = v - orig;
  if (lane == 63) off[n] = v;
}

__global__ void scan_final2(const int* __restrict__ cntE, const int* __restrict__ cntV,
                            const int* __restrict__ partE, const int* __restrict__ partV,
                            int* __restrict__ eoff, int* __restrict__ voff, int nbE) {
  __shared__ int tsum[256];
  const int t = threadIdx.x;
  const int isV = (blockIdx.x >= nbE);
  const int b = isV ? (blockIdx.x - nbE) : blockIdx.x;
  const int* cnt = isV ? cntV : cntE;
  const int* part = isV ? partV : partE;
  int* off = isV ? voff : eoff;
  const int n = isV ? N_NODES : N_EDGES_C;
  const int base = b * SCHUNK + t * 8;
  int loc[8];
  int s = 0;
#pragma unroll
  for (int q = 0; q < 8; ++q) {
    int i = base + q;
    loc[q] = (i < n) ? cnt[i] : 0;
    s += loc[q];
  }
  tsum[t] = s;
  __syncthreads();
  for (int d = 1; d < 256; d <<= 1) {
    int x = (t >= d) ? tsum[t - d] : 0;
    __syncthreads();
    tsum[t] += x;
    __syncthreads();
  }
  int run = part[b] + ((t > 0) ? tsum[t - 1] : 0);
#pragma unroll
  for (int q = 0; q < 8; ++q) {
    int i = base + q;
    if (i < n) off[i] = run;
    run += loc[q];
  }
}

__global__ void scatter_kernel(const int* __restrict__ vtx, const int* __restrict__ edg,
                               const int* __restrict__ eoff, const int* __restrict__ voff,
                               int* __restrict__ curE, int* __restrict__ curV,
                               int* __restrict__ evtx, int* __restrict__ vedg, int nnz) {
  int i = blockIdx.x * blockDim.x + threadIdx.x;
  if (i < nnz) {
    int e = edg[i], v = vtx[i];
    int p = atomicAdd(&curE[e], 1);
    evtx[eoff[e] + p] = v;
    int q = atomicAdd(&curV[v], 1);
    vedg[voff[v] + q] = e;
  }
}

// ---------------- GEMM: BK=64, swizzled LDS, dbuf counted-vmcnt, XCD-chunked 1-D grid ----------------
template <int TN>
__global__ __launch_bounds__(256) void gemm_bf16_kernel(
    const bf16* __restrict__ A, const bf16* __restrict__ B,
    bf16* __restrict__ Cb, int M, int K, int ldC, int Nstore) {
  __shared__ bf16 Al[2][128][64];
  __shared__ bf16 Bl[2][TN][64];
  const int bid = blockIdx.x;
  const int cpx = gridDim.x >> 3;
  const int wid = (bid & 7) * cpx + (bid >> 3);
  const int MBLK = (M + 127) >> 7;
  int mIdx, nIdx;
  if (TN == 128) { mIdx = wid >> 2; nIdx = wid & 3; }
  else           { mIdx = wid;      nIdx = 0; }
  if (mIdx >= MBLK) return;
  const int m0 = mIdx * 128;
  const int n0 = nIdx * TN;

  const int t = threadIdx.x;
  const int w = t >> 6, lane = t & 63;
  const int rb = (TN == 128) ? ((w >> 1) * 64) : (w * 32);
  const int cb = (TN == 128) ? ((w & 1) * 64) : 0;
  const int MF = (TN == 128) ? 4 : 2;
  const int lr = lane & 15;
  const int ls = lane >> 4;

  f32x4 acc[(TN == 128) ? 4 : 2][4];
#pragma unroll
  for (int m = 0; m < MF; ++m)
#pragma unroll
    for (int n = 0; n < 4; ++n) acc[m][n] = (f32x4){0.f, 0.f, 0.f, 0.f};

  const int srow8 = lane >> 3;
  const int scol = ((lane & 7) ^ srow8) << 3;

  const bf16* Abase = A + (size_t)m0 * K;
  const bf16* Bbase = B + (size_t)n0 * K;

#define STAGE(tile, bsel)                                                          \
  {                                                                                \
    const int kk_ = (tile) * 64;                                                   \
    _Pragma("unroll")                                                              \
    for (int q = 0; q < 4; ++q) {                                                  \
      const int row = w * 32 + q * 8 + srow8;                                      \
      gload_lds16(Abase + (size_t)row * K + kk_ + scol, &Al[bsel][w*32+q*8][0]);   \
    }                                                                              \
    _Pragma("unroll")                                                              \
    for (int q = 0; q < TN / 32; ++q) {                                            \
      const int row = w * (TN / 4) + q * 8 + srow8;                                \
      gload_lds16(Bbase + (size_t)row * K + kk_ + scol,                            \
                  &Bl[bsel][w * (TN / 4) + q * 8][0]);                             \
    }                                                                              \
  }

  const int NT = K >> 6;
  STAGE(0, 0);
  for (int tt = 0; tt < NT; ++tt) {
    const int cur = tt & 1;
    if (tt + 1 < NT) {
      STAGE(tt + 1, cur ^ 1);
      if (TN == 128) asm volatile("s_waitcnt vmcnt(8)" ::: "memory");
      else           asm volatile("s_waitcnt vmcnt(6)" ::: "memory");
    } else {
      asm volatile("s_waitcnt vmcnt(0)" ::: "memory");
    }
    __builtin_amdgcn_s_barrier();
    __builtin_amdgcn_s_setprio(1);
#pragma unroll
    for (int ks = 0; ks < 2; ++ks) {
      bf16x8 af[(TN == 128) ? 4 : 2], bfr[4];
#pragma unroll
      for (int m = 0; m < MF; ++m) {
        const int R = rb + m * 16 + lr;
        af[m] = *(const bf16x8*)(&Al[cur][R][((ks * 4 + ls) ^ (lr & 7)) << 3]);
      }
#pragma unroll
      for (int n = 0; n < 4; ++n) {
        const int R = cb + n * 16 + lr;
        bfr[n] = *(const bf16x8*)(&Bl[cur][R][((ks * 4 + ls) ^ (lr & 7)) << 3]);
      }
#pragma unroll
      for (int m = 0; m < MF; ++m)
#pragma unroll
        for (int n = 0; n < 4; ++n)
          acc[m][n] = __builtin_amdgcn_mfma_f32_16x16x32_bf16(af[m], bfr[n], acc[m][n], 0, 0, 0);
    }
    __builtin_amdgcn_s_setprio(0);
    __builtin_amdgcn_s_barrier();
  }
#undef STAGE

  const int cr = (lane >> 4) << 2;  // C/D: col = lane&15, row = (lane>>4)*4 + i
  const int cc = lane & 15;
#pragma unroll
  for (int m = 0; m < MF; ++m) {
#pragma unroll
    for (int n = 0; n < 4; ++n) {
      int gc = n0 + cb + n * 16 + cc;
      if (gc >= Nstore) continue;
#pragma unroll
      for (int i = 0; i < 4; ++i) {
        int gr = m0 + rb + m * 16 + cr + i;
        if (gr < M) Cb[(size_t)gr * ldC + gc] = (bf16)acc[m][n][i];
      }
    }
  }
}

// ---------------- wave-per-edge aggregation (bf16, C=512), unroll-2 ----------------
__global__ __launch_bounds__(256) void edge_agg_w(
    const bf16* __restrict__ Y, const int* __restrict__ eoff, const int* __restrict__ evtx,
    const float* __restrict__ degE, bf16* __restrict__ Xe, int nE) {
  const int wv = (blockIdx.x * 256 + threadIdx.x) >> 6;
  if (wv >= nE) return;
  const int lane = threadIdx.x & 63;
  const int beg = eoff[wv], end = eoff[wv + 1];
  const int cnt = end - beg;
  const float scale = (cnt > 0) ? degE[wv] / (float)cnt : 0.f;
  float acc[8] = {0.f, 0.f, 0.f, 0.f, 0.f, 0.f, 0.f, 0.f};
  for (int base = beg; base < end; base += 64) {
    const int nb = min(64, end - base);
    int myidx = (lane < nb) ? evtx[base + lane] : 0;
    int j = 0;
    for (; j + 1 < nb; j += 2) {
      const int i0 = __shfl(myidx, j);
      const int i1 = __shfl(myidx, j + 1);
      bf16x8 v0 = *(const bf16x8*)(Y + (size_t)i0 * 512 + lane * 8);
      bf16x8 v1 = *(const bf16x8*)(Y + (size_t)i1 * 512 + lane * 8);
#pragma unroll
      for (int q = 0; q < 8; ++q) acc[q] += (float)v0[q] + (float)v1[q];
    }
    if (j < nb) {
      const int i0 = __shfl(myidx, j);
      bf16x8 v0 = *(const bf16x8*)(Y + (size_t)i0 * 512 + lane * 8);
#pragma unroll
      for (int q = 0; q < 8; ++q) acc[q] += (float)v0[q];
    }
  }
  bf16x8 o;
#pragma unroll
  for (int q = 0; q < 8; ++q) o[q] = (bf16)(acc[q] * scale);
  *(bf16x8*)(Xe + (size_t)wv * 512 + lane * 8) = o;
}

// ---------------- wave-per-vertex aggregation (bf16, relu, C=512), unroll-2 ----------------
__global__ __launch_bounds__(256) void vtx_agg_w(
    const bf16* __restrict__ Xe, const int* __restrict__ voff, const int* __restrict__ vedg,
    const float* __restrict__ degV, bf16* __restrict__ outB, int nV) {
  const int wv = (blockIdx.x * 256 + threadIdx.x) >> 6;
  if (wv >= nV) return;
  const int lane = threadIdx.x & 63;
  const int beg = voff[wv], end = voff[wv + 1];
  const float dv = degV[wv];
  float acc[8] = {0.f, 0.f, 0.f, 0.f, 0.f, 0.f, 0.f, 0.f};
  for (int base = beg; base < end; base += 64) {
    const int nb = min(64, end - base);
    int myidx = (lane < nb) ? vedg[base + lane] : 0;
    int j = 0;
    for (; j + 1 < nb; j += 2) {
      const int i0 = __shfl(myidx, j);
      const int i1 = __shfl(myidx, j + 1);
      bf16x8 v0 = *(const bf16x8*)(Xe + (size_t)i0 * 512 + lane * 8);
      bf16x8 v1 = *(const bf16x8*)(Xe + (size_t)i1 * 512 + lane * 8);
#pragma unroll
      for (int q = 0; q < 8; ++q) acc[q] += (float)v0[q] + (float)v1[q];
    }
    if (j < nb) {
      const int i0 = __shfl(myidx, j);
      bf16x8 v0 = *(const bf16x8*)(Xe + (size_t)i0 * 512 + lane * 8);
#pragma unroll
      for (int q = 0; q < 8; ++q) acc[q] += (float)v0[q];
    }
  }
  bf16x8 o;
#pragma unroll
  for (int q = 0; q < 8; ++q) o[q] = (bf16)fmaxf(acc[q] * dv, 0.f);
  *(bf16x8*)(outB + (size_t)wv * 512 + lane * 8) = o;
}

// ---------------- layer-3 edge aggregation, octet layout (C=64 padded) ----------------
__global__ __launch_bounds__(256) void edge_agg40_w8(
    const bf16* __restrict__ Y, const int* __restrict__ eoff, const int* __restrict__ evtx,
    const float* __restrict__ degE, bf16* __restrict__ Xe, int nE) {
  const int wv = (blockIdx.x * 256 + threadIdx.x) >> 6;
  if (wv >= nE) return;
  const int lane = threadIdx.x & 63;
  const int g = lane >> 3, c = lane & 7;
  const int beg = eoff[wv], end = eoff[wv + 1];
  const int cnt = end - beg;
  const float scale = (cnt > 0) ? degE[wv] / (float)cnt : 0.f;
  float acc[8] = {0.f, 0.f, 0.f, 0.f, 0.f, 0.f, 0.f, 0.f};
  for (int base = beg; base < end; base += 64) {
    const int nb = min(64, end - base);
    int myidx = (lane < nb) ? evtx[base + lane] : 0;
    for (int inner = 0; inner < 8; ++inner) {
      const int r = inner * 8 + g;
      if (inner * 8 >= nb) break;
      const int ridx = __shfl(myidx, r);
      if (r < nb) {
        bf16x8 v = *(const bf16x8*)(Y + (size_t)ridx * 64 + c * 8);
#pragma unroll
        for (int q = 0; q < 8; ++q) acc[q] += (float)v[q];
      }
    }
  }
#pragma unroll
  for (int o = 8; o < 64; o <<= 1)
#pragma unroll
    for (int q = 0; q < 8; ++q) acc[q] += __shfl_xor(acc[q], o);
  if (lane < 8) {
    bf16x8 o;
#pragma unroll
    for (int q = 0; q < 8; ++q) o[q] = (bf16)(acc[q] * scale);
    *(bf16x8*)(Xe + (size_t)wv * 64 + lane * 8) = o;
  }
}

// ---------------- final vertex aggregation + log_softmax, octet layout ----------------
__global__ __launch_bounds__(256) void vtx_agg_lsm8(
    const bf16* __restrict__ Xe, const int* __restrict__ voff, const int* __restrict__ vedg,
    const float* __restrict__ degV, float* __restrict__ out, int nV) {
  const int wv = (blockIdx.x * 256 + threadIdx.x) >> 6;
  if (wv >= nV) return;
  const int lane = threadIdx.x & 63;
  const int g = lane >> 3, c = lane & 7;
  const int beg = voff[wv], end = voff[wv + 1];
  const float dv = degV[wv];
  float acc[8] = {0.f, 0.f, 0.f, 0.f, 0.f, 0.f, 0.f, 0.f};
  for (int base = beg; base < end; base += 64) {
    const int nb = min(64, end - base);
    int myidx = (lane < nb) ? vedg[base + lane] : 0;
    for (int inner = 0; inner < 8; ++inner) {
      const int r = inner * 8 + g;
      if (inner * 8 >= nb) break;
      const int ridx = __shfl(myidx, r);
      if (r < nb) {
        bf16x8 v = *(const bf16x8*)(Xe + (size_t)ridx * 64 + c * 8);
#pragma unroll
        for (int q = 0; q < 8; ++q) acc[q] += (float)v[q];
      }
    }
  }
#pragma unroll
  for (int o = 8; o < 64; o <<= 1)
#pragma unroll
    for (int q = 0; q < 8; ++q) acc[q] += __shfl_xor(acc[q], o);
  float l[8];
#pragma unroll
  for (int q = 0; q < 8; ++q) l[q] = acc[q] * dv;
  float lm = -3.4e38f;
  if (c < 5) {
#pragma unroll
    for (int q = 0; q < 8; ++q) lm = fmaxf(lm, l[q]);
  }
#pragma unroll
  for (int o = 1; o < 8; o <<= 1) lm = fmaxf(lm, __shfl_xor(lm, o));
  float ls = 0.f;
  if (c < 5) {
#pragma unroll
    for (int q = 0; q < 8; ++q) ls += expf(l[q] - lm);
  }
#pragma unroll
  for (int o = 1; o < 8; o <<= 1) ls += __shfl_xor(ls, o);
  const float lg = logf(ls);
  if (lane < 5) {
    f32x8 w;
#pragma unroll
    for (int q = 0; q < 8; ++q) w[q] = l[q] - lm - lg;
    *(f32x8*)(out + (size_t)wv * 40 + lane * 8) = w;
  }
}

extern "C" void kernel_launch(void* const* d_in, const int* in_sizes, int n_in,
                              void* d_out, int out_size, void* d_ws, size_t ws_size,
                              hipStream_t stream) {
  (void)in_sizes; (void)n_in; (void)out_size; (void)ws_size;
  const float* X = (const float*)d_in[0];
  const int* vertex = (const int*)d_in[1];
  const int* edges = (const int*)d_in[2];
  const float* W1 = (const float*)d_in[3];
  const float* W2 = (const float*)d_in[4];
  const float* Wout = (const float*)d_in[5];
  const float* degE = (const float*)d_in[6];
  const float* degV = (const float*)d_in[7];
  float* out = (float*)d_out;

  char* ws = (char*)d_ws;
  size_t off = 0;
  auto alloc = [&](size_t bytes) -> void* {
    void* p = ws + off;
    off += (bytes + 255) & ~(size_t)255;
    return p;
  };
  bf16* Xb  = (bf16*)alloc((size_t)N_NODES * 512 * sizeof(bf16));   // vertex features H
  bf16* XeB = (bf16*)alloc((size_t)N_EDGES_C * 512 * sizeof(bf16)); // edge agg of H
  bf16* YeB = (bf16*)alloc((size_t)N_EDGES_C * 512 * sizeof(bf16)); // XeB @ W
  bf16* Y40b  = (bf16*)alloc((size_t)N_NODES * 64 * sizeof(bf16));
  bf16* Xe40b = (bf16*)alloc((size_t)N_EDGES_C * 64 * sizeof(bf16));
  bf16* Wt1 = (bf16*)alloc((size_t)512 * 512 * sizeof(bf16));
  bf16* Wt2 = (bf16*)alloc((size_t)512 * 512 * sizeof(bf16));
  bf16* Wt3 = (bf16*)alloc((size_t)64 * 512 * sizeof(bf16));
  int* eoff = (int*)alloc((N_EDGES_C + 1) * sizeof(int));
  int* voff = (int*)alloc((N_NODES + 1) * sizeof(int));
  int* evtx = (int*)alloc((size_t)NNZ_C * sizeof(int));
  int* vedg = (int*)alloc((size_t)NNZ_C * sizeof(int));
  int* cnts = (int*)alloc((size_t)(2 * (N_EDGES_C + N_NODES)) * sizeof(int));
  int* cntE = cnts;
  int* cntV = cnts + N_EDGES_C;
  int* curE = cnts + N_EDGES_C + N_NODES;
  int* curV = cnts + 2 * N_EDGES_C + N_NODES;
  int* partE = (int*)alloc(64 * sizeof(int));
  int* partV = (int*)alloc(64 * sizeof(int));

  hipMemsetAsync(cnts, 0, (size_t)(2 * (N_EDGES_C + N_NODES)) * sizeof(int), stream);

  prep_conv<<<PREP_TOTAL, 256, 0, stream>>>(
      W1, W2, Wout, X, Wt1, Wt2, Wt3, Xb, vertex, edges, cntV, cntE);

  const int nbE = (N_EDGES_C + SCHUNK - 1) / SCHUNK;  // 13
  const int nbV = (N_NODES + SCHUNK - 1) / SCHUNK;    // 25
  scan_part2<<<nbE + nbV, 256, 0, stream>>>(cntE, cntV, partE, partV, nbE);
  scan_mid2<<<1, 128, 0, stream>>>(partE, partV, eoff, voff, nbE, nbV);
  scan_final2<<<nbE + nbV, 256, 0, stream>>>(cntE, cntV, partE, partV, eoff, voff, nbE);

  scatter_kernel<<<(NNZ_C + 255) / 256, 256, 0, stream>>>(vertex, edges, eoff, voff,
                                                          curE, curV, evtx, vedg, NNZ_C);

  const int MBV = (N_NODES + 127) / 128;          // 391
  const int MBE = (N_EDGES_C + 127) / 128;        // 196
  const int GE512 = ((MBE * 4 + 7) / 8) * 8;      // 784
  const int GV64  = ((MBV + 7) / 8) * 8;          // 392

  // ---- layer 1: edge_agg(X) -> GEMM (25K rows) -> vtx_agg ----
  edge_agg_w<<<(N_EDGES_C + 3) / 4, 256, 0, stream>>>(Xb, eoff, evtx, degE, XeB, N_EDGES_C);
  gemm_bf16_kernel<128><<<GE512, 256, 0, stream>>>(XeB, Wt1, YeB, N_EDGES_C, 512, 512, 512);
  vtx_agg_w<<<(N_NODES + 3) / 4, 256, 0, stream>>>(YeB, voff, vedg, degV, Xb, N_NODES);

  // ---- layer 2 ----
  edge_agg_w<<<(N_EDGES_C + 3) / 4, 256, 0, stream>>>(Xb, eoff, evtx, degE, XeB, N_EDGES_C);
  gemm_bf16_kernel<128><<<GE512, 256, 0, stream>>>(XeB, Wt2, YeB, N_EDGES_C, 512, 512, 512);
  vtx_agg_w<<<(N_NODES + 3) / 4, 256, 0, stream>>>(YeB, voff, vedg, degV, Xb, N_NODES);

  // ---- layer 3 ----
  gemm_bf16_kernel<64><<<GV64, 256, 0, stream>>>(Xb, Wt3, Y40b, N_NODES, 512, 64, 64);
  edge_agg40_w8<<<(N_EDGES_C + 3) / 4, 256, 0, stream>>>(Y40b, eoff, evtx, degE, Xe40b, N_EDGES_C);
  vtx_agg_lsm8<<<(N_NODES + 3) / 4, 256, 0, stream>>>(Xe40b, voff, vedg, degV, out, N_NODES);
}